// Round 1
// baseline (503.674 us; speedup 1.0000x reference)
//
#include <hip/hip_runtime.h>

// TensorTrain: BS=16384, N_CH=8, H=256, RANK=16, N_AGGR=4, T=64, R=(16+1)*16=272
// Only r < 256 of ris is used (U_rank rows 0..15, b_rank = row 15 of tile 15).
//
// Round-3 design: same compute structure as round-2 (block = 1024 thr = 16 waves
// = 4 aggr x 4 sample-groups, 64 samples/block, grid = 256), but the per-tile
// __syncthreads() (which drains vmcnt(0) and serialized every tile behind its
// own prefetch) is replaced by a T3/T4-style counted-vmcnt pipeline:
//   - 3 B-tile LDS buffers (96 KB), global_load_lds issued 2 tiles ahead
//   - per tile: s_waitcnt vmcnt(2) + raw s_barrier  (each wave issues exactly
//     2 loads/tile, so vmcnt(2) == "my tile-t loads landed, t+1 may fly")
//   - vmcnt never drains to 0 in the main loop (only at the 8 channel
//     boundaries where the A-stage f32 loads force it anyway)
//   - inner 16-tile loop fully unrolled: bb[t]/srcl/extra compile-time
//     (removes runtime-indexed array -> scratch), s_setprio(1) around MFMAs.

#define N_CH   8
#define H_DIM  256
#define R_FULL 272

typedef __bf16 bf16x8 __attribute__((ext_vector_type(8)));
typedef float  f32x4  __attribute__((ext_vector_type(4)));

union BF8 {
  bf16x8 v;
  unsigned short s[8];
  uint4 q;
};

typedef __attribute__((address_space(3))) unsigned int       lds_u32;
typedef __attribute__((address_space(1))) const unsigned int glb_u32;

static __device__ __forceinline__ unsigned short f2bf(float x) {
  union { float f; unsigned int u; } t; t.f = x;
  unsigned int u = t.u;
  return (unsigned short)((u + 0x7FFFu + ((u >> 16) & 1u)) >> 16); // RNE
}
static __device__ __forceinline__ unsigned int pk2(float a, float b) {
  return (unsigned int)f2bf(a) | ((unsigned int)f2bf(b) << 16);
}
static __device__ __forceinline__ void ll16(const void* g, void* l) {
  __builtin_amdgcn_global_load_lds((glb_u32*)g, (lds_u32*)l, 16, 0, 0);
}

// ---- prep: U[c][a][h][r<256] f32 -> bf16 in MFMA B-fragment order:
// Ubf[ca][t][ks][lane][j]  (j=0..7 bf16, 16B per lane-frag), where
//   r = t*16 + (lane&15), h = ks*32 + (lane>>4)*8 + j.
__global__ void prep_U_kernel(const float* __restrict__ U, unsigned int* __restrict__ Ubf) {
  unsigned int idx  = blockIdx.x * 256u + threadIdx.x;   // 1,048,576 total
  unsigned int jp   = idx & 3u;
  unsigned int lane = (idx >> 2) & 63u;
  unsigned int ks   = (idx >> 8) & 7u;
  unsigned int t    = (idx >> 11) & 15u;
  unsigned int ca   = idx >> 15;
  unsigned int h = ks * 32u + (lane >> 4) * 8u + jp * 2u;
  unsigned int r = t * 16u + (lane & 15u);
  const float* src = U + ((size_t)ca * 256u + h) * R_FULL + r;
  Ubf[idx] = pk2(src[0], src[R_FULL]);   // h, h+1
}

// LDS layout (dynamic, 128 KB):
//   A frags:  [sg][ks][lane] 16B          -> 32 KB   at offset 0
//   B bufs:   3 x ([aggr][ks][lane] 16B)  -> 3x32 KB at offset 32K/64K/96K
#define SM_A    0
#define SM_B(k) (32768 + (k) * 32768)

__global__ __launch_bounds__(1024)
void tt_main(const float* __restrict__ nh,            // (BS, 8, 256)
             const float* __restrict__ ty,            // (BS, 64)
             const char*  __restrict__ Ubf,           // frag-ordered bf16 U (4 MB)
             const float* __restrict__ bB,            // (8, 4, 1, 272)
             const float* __restrict__ Ut,            // (4, 64, 16)
             const float* __restrict__ bt,            // (4, 1, 16)
             const float* __restrict__ Uo,            // (4, 16, 256)
             const float* __restrict__ bo,            // (4, 1, 256)
             float* __restrict__ out)                 // (BS, 1024)
{
  extern __shared__ char smem[];
  const int tid  = threadIdx.x;
  const int lane = tid & 63;
  const int w    = tid >> 6;        // 0..15
  const int a    = w & 3;           // aggregator
  const int sg   = w >> 2;          // sample group (16 samples)
  const int b0   = blockIdx.x * 64; // block sample base
  const int row0 = b0 + sg * 16;    // wave sample base
  const int lr   = lane & 15;
  const int lg   = lane >> 4;

  // ---- carry init: rank_ris0 = ty @ U_type[a] + b_type[a]  (K=64 -> 2 MFMAs)
  // (all its loads are consumed by the MFMAs, so vmcnt is fully retired before
  //  the B prefetches below are issued -> loop vmcnt counting sees only B loads)
  f32x4 carry;
  {
    float btv = bt[a * 16 + lr];
    f32x4 acc = { btv, btv, btv, btv };
#pragma unroll
    for (int ks = 0; ks < 2; ++ks) {
      BF8 utf, af;
#pragma unroll
      for (int j = 0; j < 8; ++j) {
        utf.s[j] = f2bf(Ut[a * 1024 + (ks * 32 + lg * 8 + j) * 16 + lr]);
        af.s[j]  = f2bf(ty[(size_t)(row0 + lr) * 64 + ks * 32 + lg * 8 + j]);
      }
      acc = __builtin_amdgcn_mfma_f32_16x16x32_bf16(af.v, utf.v, acc, 0, 0, 0);
    }
    carry = acc;
  }

  // B-tile async loader for global tile g = c*16 + t: wave w copies chunks
  // 2w, 2w+1 (chunk = (aggr,ks) = 1KB) -> exactly 2 vmem loads per wave.
  auto issueB = [&](int g) {
    const int cB  = g >> 4;
    const int tB  = g & 15;
    const int bo_ = SM_B(g % 3);
#pragma unroll
    for (int q = 0; q < 2; ++q) {
      const int ch = w * 2 + q;                       // 0..31
      const char* gp = Ubf + (((((size_t)cB * 4 + (ch >> 3)) * 16 + tB) * 8 + (ch & 7)) << 10)
                           + lane * 16;
      ll16(gp, smem + bo_ + ch * 1024);
    }
  };

  issueB(0);
  issueB(1);

  BF8   Af[8];
  float bb[16];
  f32x4 partial;

  // ---- channel scan, pipelined: at tile g, B(g) is in LDS (vmcnt(2)+barrier),
  // B(g+1) is in flight, B(g+2) is issued here.
#pragma unroll 1
  for (int c = 0; c < N_CH; ++c) {
#pragma unroll
    for (int t = 0; t < 16; ++t) {
      const int g = c * 16 + t;

      // my 2 loads for tile g retired; tile g+1's 2 may remain outstanding
      if (t == 15 && c == N_CH - 1) asm volatile("s_waitcnt vmcnt(0)");
      else                          asm volatile("s_waitcnt vmcnt(2)");
      // all waves' tile-g chunks landed; all waves done reading buf (g-1)%3
      __builtin_amdgcn_s_barrier();

      if (t == 0) {
        // stage A (this block's 64 samples, channel c) into LDS fragment order.
        // The f32 loads here drain the B prefetch (they are newest in vmcnt);
        // that only costs depth at the 8 channel boundaries.
        {
          const int sg_s = tid >> 8;
          const int ksh  = (tid >> 6) & 3;
          const int ln   = tid & 63;
          const int row  = sg_s * 16 + (ln & 15);
#pragma unroll
          for (int p = 0; p < 2; ++p) {
            const int ks = ksh * 2 + p;
            const int k0 = ks * 32 + (ln >> 4) * 8;
            const float* s = nh + ((size_t)(b0 + row) * N_CH + c) * H_DIM + k0;
            float4 x0 = *(const float4*)s;
            float4 x1 = *(const float4*)(s + 4);
            uint4 qv;
            qv.x = pk2(x0.x, x0.y); qv.y = pk2(x0.z, x0.w);
            qv.z = pk2(x1.x, x1.y); qv.w = pk2(x1.z, x1.w);
            *(uint4*)(smem + SM_A + ((sg_s * 8 + ks) * 64 + ln) * 16) = qv;
          }
        }
        asm volatile("s_waitcnt lgkmcnt(0)");     // my ds_writes landed
        __builtin_amdgcn_s_barrier();             // everyone's A visible
#pragma unroll
        for (int ks = 0; ks < 8; ++ks)
          Af[ks].q = *(const uint4*)(smem + SM_A + ((sg * 8 + ks) * 64 + lane) * 16);
        const float* bBp = bB + (c * 4 + a) * R_FULL;
#pragma unroll
        for (int t2 = 0; t2 < 16; ++t2) bb[t2] = bBp[t2 * 16 + lr];
        partial[0] = partial[1] = partial[2] = partial[3] = 0.f;
      }

      // issue tile g+2 into buf (g+2)%3: last read at tile g-1, which every
      // wave finished before this tile's barrier (lgkm waits precede MFMAs
      // which precede the barrier in program order).
      if (g + 2 < N_CH * 16) issueB(g + 2);

      const int bufoff = SM_B((c + t) % 3);   // (c*16+t)%3 == (c+t)%3
      f32x4 acc = { bb[t], bb[t], bb[t], bb[t] };
      uint4 Bq[8];
#pragma unroll
      for (int ks = 0; ks < 8; ++ks)
        Bq[ks] = *(const uint4*)(smem + bufoff + (a * 8 + ks) * 1024 + lane * 16);
      __builtin_amdgcn_s_setprio(1);
#pragma unroll
      for (int ks = 0; ks < 8; ++ks) {
        BF8 bf; bf.q = Bq[ks];
        acc = __builtin_amdgcn_mfma_f32_16x16x32_bf16(Af[ks].v, bf.v, acc, 0, 0, 0);
      }
      __builtin_amdgcn_s_setprio(0);

      // fused scan step: partial += carry[r=t] * acc   (+ bias row at t=15)
      const float extra = (t == 15) ? 1.0f : 0.0f;
      const int   srcl  = (lane & 48) | t;
#pragma unroll
      for (int i = 0; i < 4; ++i) {
        float cv = __shfl(carry[i], srcl, 64) + extra;
        partial[i] += cv * acc[i];
      }
    }
    carry = partial;
  }

  // ---- epilogue: out[b][a*256+h] = carry[b][a][:] @ Uo[a][:][h] + bo[a][h]
  float uo[4][16], bov[4];
#pragma unroll
  for (int chk = 0; chk < 4; ++chk) {
    bov[chk] = bo[a * 256 + chk * 64 + lane];
#pragma unroll
    for (int r = 0; r < 16; ++r)
      uo[chk][r] = Uo[(size_t)a * 4096 + r * 256 + chk * 64 + lane];
  }
#pragma unroll
  for (int gq = 0; gq < 4; ++gq)
#pragma unroll
    for (int i = 0; i < 4; ++i) {
      const int m = gq * 4 + i;
      float cv[16];
#pragma unroll
      for (int r = 0; r < 16; ++r) cv[r] = __shfl(carry[i], (gq << 4) | r, 64);
#pragma unroll
      for (int chk = 0; chk < 4; ++chk) {
        float v = bov[chk];
#pragma unroll
        for (int r = 0; r < 16; ++r) v += cv[r] * uo[chk][r];
        out[(size_t)(row0 + m) * 1024 + a * 256 + chk * 64 + lane] = v;
      }
    }
}

extern "C" void kernel_launch(void* const* d_in, const int* in_sizes, int n_in,
                              void* d_out, int out_size, void* d_ws, size_t ws_size,
                              hipStream_t stream) {
  const float* nh = (const float*)d_in[0];   // neighbour_h (16384, 8, 256)
  const float* ty = (const float*)d_in[1];   // type_embs   (16384, 64)
  const float* U  = (const float*)d_in[2];   // U           (8, 4, 256, 272)
  const float* bB = (const float*)d_in[3];   // b           (8, 4, 1, 272)
  const float* Ut = (const float*)d_in[4];   // U_type      (4, 64, 16)
  const float* bt = (const float*)d_in[5];   // b_type      (4, 1, 16)
  const float* Uo = (const float*)d_in[6];   // U_output    (4, 16, 256)
  const float* bo = (const float*)d_in[7];   // b_output    (4, 1, 256)
  float* out = (float*)d_out;

  unsigned int* Ubf32 = (unsigned int*)d_ws; // 4 MB frag-ordered bf16 U

  prep_U_kernel<<<4096, 256, 0, stream>>>(U, Ubf32);

  (void)hipFuncSetAttribute((const void*)tt_main,
                            hipFuncAttributeMaxDynamicSharedMemorySize, 131072);
  tt_main<<<256, 1024, 131072, stream>>>(nh, ty, (const char*)d_ws,
                                         bB, Ut, bt, Uo, bo, out);
}

// Round 2
// 361.664 us; speedup vs baseline: 1.3927x; 1.3927x over previous
//
#include <hip/hip_runtime.h>

// TensorTrain: BS=16384, N_CH=8, H=256, RANK=16, N_AGGR=4, T=64, R=(16+1)*16=272
// Only r < 256 of ris is used (U_rank rows 0..15, b_rank = row 15 of tile 15).
//
// Round-4: counted-vmcnt pipeline (round-3 idea) with register pressure fixed:
//   - __launch_bounds__(1024, 4): truth-in-advertising occupancy (1 block/CU,
//     128 KB+ dynamic LDS) -> 128-VGPR budget, no scratch spills (round-3 had
//     VGPR=64 + 665 MB/dispatch of spill traffic).
//   - 4 B-tile LDS buffers (128 KB); tile loop is tb(runtime) x k(unrolled 4),
//     so buffer index = k is compile-time and only one tile's Bq is live.
//   - bias bb[16] reg array (scratch seed) -> 4 KB LDS region, one
//     ds_read_b32 per tile.
//   - A staged transiently into B-buffer 3 at t==0 (Af -> regs immediately;
//     buf3's next async write, issueB(g+3) at t==1, lands after all waves'
//     Af reads by barrier ordering). LDS total 132 KB.
//   - per tile: s_waitcnt vmcnt(2) + raw s_barrier; vmcnt never drains to 0
//     in the main loop except the 8 channel boundaries (A-stage f32 loads).

#define N_CH   8
#define H_DIM  256
#define R_FULL 272

typedef __bf16 bf16x8 __attribute__((ext_vector_type(8)));
typedef float  f32x4  __attribute__((ext_vector_type(4)));

union BF8 {
  bf16x8 v;
  unsigned short s[8];
  uint4 q;
};

typedef __attribute__((address_space(3))) unsigned int       lds_u32;
typedef __attribute__((address_space(1))) const unsigned int glb_u32;

static __device__ __forceinline__ unsigned short f2bf(float x) {
  union { float f; unsigned int u; } t; t.f = x;
  unsigned int u = t.u;
  return (unsigned short)((u + 0x7FFFu + ((u >> 16) & 1u)) >> 16); // RNE
}
static __device__ __forceinline__ unsigned int pk2(float a, float b) {
  return (unsigned int)f2bf(a) | ((unsigned int)f2bf(b) << 16);
}
static __device__ __forceinline__ void ll16(const void* g, void* l) {
  __builtin_amdgcn_global_load_lds((glb_u32*)g, (lds_u32*)l, 16, 0, 0);
}

// ---- prep: U[c][a][h][r<256] f32 -> bf16 in MFMA B-fragment order:
// Ubf[ca][t][ks][lane][j]  (j=0..7 bf16, 16B per lane-frag), where
//   r = t*16 + (lane&15), h = ks*32 + (lane>>4)*8 + j.
__global__ void prep_U_kernel(const float* __restrict__ U, unsigned int* __restrict__ Ubf) {
  unsigned int idx  = blockIdx.x * 256u + threadIdx.x;   // 1,048,576 total
  unsigned int jp   = idx & 3u;
  unsigned int lane = (idx >> 2) & 63u;
  unsigned int ks   = (idx >> 8) & 7u;
  unsigned int t    = (idx >> 11) & 15u;
  unsigned int ca   = idx >> 15;
  unsigned int h = ks * 32u + (lane >> 4) * 8u + jp * 2u;
  unsigned int r = t * 16u + (lane & 15u);
  const float* src = U + ((size_t)ca * 256u + h) * R_FULL + r;
  Ubf[idx] = pk2(src[0], src[R_FULL]);   // h, h+1
}

// LDS layout (dynamic, 132 KB):
//   B bufs:  4 x ([aggr][ks][lane] 16B) = 4 x 32 KB at 0/32K/64K/96K
//            (buf 3 doubles as the transient A-stage area at t==0)
//   bias:    [a][r<256] f32, 4 KB at 128 KB
#define SM_B(q)  ((q) * 32768)
#define SM_BIAS  131072

__global__ __launch_bounds__(1024, 4)
void tt_main(const float* __restrict__ nh,            // (BS, 8, 256)
             const float* __restrict__ ty,            // (BS, 64)
             const char*  __restrict__ Ubf,           // frag-ordered bf16 U (4 MB)
             const float* __restrict__ bB,            // (8, 4, 1, 272)
             const float* __restrict__ Ut,            // (4, 64, 16)
             const float* __restrict__ bt,            // (4, 1, 16)
             const float* __restrict__ Uo,            // (4, 16, 256)
             const float* __restrict__ bo,            // (4, 1, 256)
             float* __restrict__ out)                 // (BS, 1024)
{
  extern __shared__ char smem[];
  const int tid  = threadIdx.x;
  const int lane = tid & 63;
  const int w    = tid >> 6;        // 0..15
  const int a    = w & 3;           // aggregator
  const int sg   = w >> 2;          // sample group (16 samples)
  const int b0   = blockIdx.x * 64; // block sample base
  const int row0 = b0 + sg * 16;    // wave sample base
  const int lr   = lane & 15;
  const int lg   = lane >> 4;

  // ---- carry init: rank_ris0 = ty @ U_type[a] + b_type[a]  (K=64 -> 2 MFMAs)
  // (all loads here are consumed before the B prefetches below are issued, so
  //  the loop's vmcnt counting only sees B loads)
  f32x4 carry;
  {
    float btv = bt[a * 16 + lr];
    f32x4 acc = { btv, btv, btv, btv };
#pragma unroll
    for (int ks = 0; ks < 2; ++ks) {
      BF8 utf, af;
#pragma unroll
      for (int j = 0; j < 8; ++j) {
        utf.s[j] = f2bf(Ut[a * 1024 + (ks * 32 + lg * 8 + j) * 16 + lr]);
        af.s[j]  = f2bf(ty[(size_t)(row0 + lr) * 64 + ks * 32 + lg * 8 + j]);
      }
      acc = __builtin_amdgcn_mfma_f32_16x16x32_bf16(af.v, utf.v, acc, 0, 0, 0);
    }
    carry = acc;
  }

  // B-tile async loader for global tile g = c*16 + t: wave w copies chunks
  // 2w, 2w+1 (chunk = (aggr,ks) = 1KB) -> exactly 2 vmem loads per wave.
  // Buffer = g & 3  (c*16 is a multiple of 4, so g & 3 == t & 3).
  auto issueB = [&](int g) {
    const int cB  = g >> 4;
    const int tB  = g & 15;
    const int bo_ = SM_B(g & 3);
#pragma unroll
    for (int q = 0; q < 2; ++q) {
      const int ch = w * 2 + q;                       // 0..31
      const char* gp = Ubf + (((((size_t)cB * 4 + (ch >> 3)) * 16 + tB) * 8 + (ch & 7)) << 10)
                           + lane * 16;
      ll16(gp, smem + bo_ + ch * 1024);
    }
  };

  issueB(0);
  issueB(1);

  BF8 Af[8];
  const int bias_base = SM_BIAS + (a * 256 + lr) * 4;   // + t*64 per tile

  // ---- channel scan, pipelined: at tile g, B(g) is in LDS (vmcnt(2)+barrier),
  // B(g+1) is in flight, B(g+2) is issued after this tile's barrier.
#pragma unroll 1
  for (int c = 0; c < N_CH; ++c) {
    f32x4 partial = { 0.f, 0.f, 0.f, 0.f };
#pragma unroll 1
    for (int tb = 0; tb < 4; ++tb) {
#pragma unroll
      for (int k = 0; k < 4; ++k) {
        const int t = tb * 4 + k;          // k compile-time, tb runtime
        const int g = c * 16 + t;

        // my 2 loads for tile g retired; tile g+1's 2 may remain outstanding
        if (k == 3 && (c * 4 + tb == 31)) {
          asm volatile("s_waitcnt vmcnt(0)" ::: "memory");   // final tile
        } else {
          asm volatile("s_waitcnt vmcnt(2)" ::: "memory");
        }
        // all waves' tile-g chunks landed; all waves done reading buf (g-1)&3
        __builtin_amdgcn_s_barrier();

        if (k == 0 && tb == 0) {
          // stage A (64 samples, channel c) into buf 3 + bias into SM_BIAS.
          // The f32 loads drain the B prefetch (newest in vmcnt) -- costs
          // pipeline depth only at the 8 channel boundaries.
          {
            const int sg_s = tid >> 8;
            const int ksh  = (tid >> 6) & 3;
            const int ln   = tid & 63;
            const int row  = sg_s * 16 + (ln & 15);
#pragma unroll
            for (int p = 0; p < 2; ++p) {
              const int ks = ksh * 2 + p;
              const int k0 = ks * 32 + (ln >> 4) * 8;
              const float* s = nh + ((size_t)(b0 + row) * N_CH + c) * H_DIM + k0;
              float4 x0 = *(const float4*)s;
              float4 x1 = *(const float4*)(s + 4);
              uint4 qv;
              qv.x = pk2(x0.x, x0.y); qv.y = pk2(x0.z, x0.w);
              qv.z = pk2(x1.x, x1.y); qv.w = pk2(x1.z, x1.w);
              *(uint4*)(smem + SM_B(3) + ((sg_s * 8 + ks) * 64 + ln) * 16) = qv;
            }
          }
          {
            const int a_s = tid >> 8;        // 0..3
            const int r_s = tid & 255;       // 0..255
            *(float*)(smem + SM_BIAS + (a_s * 256 + r_s) * 4) =
                bB[(c * 4 + a_s) * R_FULL + r_s];
          }
          asm volatile("s_waitcnt lgkmcnt(0)" ::: "memory");  // my ds_writes landed
          __builtin_amdgcn_s_barrier();                       // A + bias visible
          // Af -> regs NOW; buf 3 is free for B(g+3) (issued at t==1, whose
          // barrier follows every wave's t==0 MFMAs and hence these reads).
#pragma unroll
          for (int ks = 0; ks < 8; ++ks)
            Af[ks].q = *(const uint4*)(smem + SM_B(3) + ((sg * 8 + ks) * 64 + lane) * 16);
        }

        // issue tile g+2 into buf (g+2)&3: last read at tile g-1, finished by
        // every wave before this tile's barrier.
        if (g + 2 < N_CH * 16) issueB(g + 2);

        const float bias = *(const float*)(smem + bias_base + t * 64);
        f32x4 acc = { bias, bias, bias, bias };
        uint4 Bq[8];
#pragma unroll
        for (int ks = 0; ks < 8; ++ks)
          Bq[ks] = *(const uint4*)(smem + SM_B(k) + (a * 8 + ks) * 1024 + lane * 16);
        __builtin_amdgcn_s_setprio(1);
#pragma unroll
        for (int ks = 0; ks < 8; ++ks) {
          BF8 bf; bf.q = Bq[ks];
          acc = __builtin_amdgcn_mfma_f32_16x16x32_bf16(Af[ks].v, bf.v, acc, 0, 0, 0);
        }
        __builtin_amdgcn_s_setprio(0);

        // fused scan step: partial += carry[r=t] * acc   (+ bias row at t=15)
        const float extra = (k == 3 && tb == 3) ? 1.0f : 0.0f;
        const int   srcl  = (lane & 48) | t;
#pragma unroll
        for (int i = 0; i < 4; ++i) {
          float cv = __shfl(carry[i], srcl, 64) + extra;
          partial[i] += cv * acc[i];
        }
      }
    }
    carry = partial;
  }

  // ---- epilogue: out[b][a*256+h] = carry[b][a][:] @ Uo[a][:][h] + bo[a][h]
  float uo[4][16], bov[4];
#pragma unroll
  for (int chk = 0; chk < 4; ++chk) {
    bov[chk] = bo[a * 256 + chk * 64 + lane];
#pragma unroll
    for (int r = 0; r < 16; ++r)
      uo[chk][r] = Uo[(size_t)a * 4096 + r * 256 + chk * 64 + lane];
  }
#pragma unroll
  for (int gq = 0; gq < 4; ++gq)
#pragma unroll
    for (int i = 0; i < 4; ++i) {
      const int m = gq * 4 + i;
      float cv[16];
#pragma unroll
      for (int r = 0; r < 16; ++r) cv[r] = __shfl(carry[i], (gq << 4) | r, 64);
#pragma unroll
      for (int chk = 0; chk < 4; ++chk) {
        float v = bov[chk];
#pragma unroll
        for (int r = 0; r < 16; ++r) v += cv[r] * uo[chk][r];
        out[(size_t)(row0 + m) * 1024 + a * 256 + chk * 64 + lane] = v;
      }
    }
}

extern "C" void kernel_launch(void* const* d_in, const int* in_sizes, int n_in,
                              void* d_out, int out_size, void* d_ws, size_t ws_size,
                              hipStream_t stream) {
  const float* nh = (const float*)d_in[0];   // neighbour_h (16384, 8, 256)
  const float* ty = (const float*)d_in[1];   // type_embs   (16384, 64)
  const float* U  = (const float*)d_in[2];   // U           (8, 4, 256, 272)
  const float* bB = (const float*)d_in[3];   // b           (8, 4, 1, 272)
  const float* Ut = (const float*)d_in[4];   // U_type      (4, 64, 16)
  const float* bt = (const float*)d_in[5];   // b_type      (4, 1, 16)
  const float* Uo = (const float*)d_in[6];   // U_output    (4, 16, 256)
  const float* bo = (const float*)d_in[7];   // b_output    (4, 1, 256)
  float* out = (float*)d_out;

  unsigned int* Ubf32 = (unsigned int*)d_ws; // 4 MB frag-ordered bf16 U

  prep_U_kernel<<<4096, 256, 0, stream>>>(U, Ubf32);

  (void)hipFuncSetAttribute((const void*)tt_main,
                            hipFuncAttributeMaxDynamicSharedMemorySize, 135168);
  tt_main<<<256, 1024, 135168, stream>>>(nh, ty, (const char*)d_ws,
                                         bB, Ut, bt, Uo, bo, out);
}